// Round 1
// baseline (315.981 us; speedup 1.0000x reference)
//
#include <hip/hip_runtime.h>

// Problem constants (fixed by reference setup_inputs):
//   d: (B=64, T=12, C=64, S2=1024) fp32, m: same shape int32,
//   poi_index: (S2,) int, side=32 (ignored; S2 = side*side = 1024).
#define B_  64
#define T_  12
#define C_  64
#define S2_ 1024

// Kernel 1: flags[s] = OR over all (b,c) of m[b, T-1, c, s].
// Grid: 256 blocks (64 b-values x 4 cell-chunks), 256 threads.
// Lane i reads consecutive s -> fully coalesced. 64-deep unroll over c
// gives 64 independent loads in flight per thread.
__global__ void mask_reduce(const int* __restrict__ m, int* __restrict__ flags) {
    const int cc = blockIdx.x & 3;        // cell chunk 0..3
    const int b  = blockIdx.x >> 2;       // 0..63
    const int s  = cc * 256 + threadIdx.x;
    const int* row = m + ((size_t)(b * T_ + (T_ - 1)) * C_) * S2_ + s;
    int acc = 0;
#pragma unroll
    for (int c = 0; c < C_; ++c) acc |= row[(size_t)c * S2_];
    if (acc) atomicOr(&flags[s], 1);
}

// Kernel 2: out[b,c,s] = d[b,T-1,c,s] + (flags[s]==0 ? d[b,T-1,c,poi[s]] : 0)
// float4-vectorized; each 256-thread block covers exactly one (b,c) row of
// 1024 floats, so the conditional gathers land inside the block's own 4 KB
// row (L1-resident).
__global__ void auxcmp_main(const float* __restrict__ d,
                            const int* __restrict__ flags,
                            const int* __restrict__ poi,
                            float* __restrict__ out) {
    const int i  = (blockIdx.x * 256 + threadIdx.x) * 4;  // flat over B*C*S2
    const int bc = i >> 10;
    const int s  = i & (S2_ - 1);
    const int b  = bc >> 6;
    const int c  = bc & 63;
    const size_t dbase = ((size_t)(b * T_ + (T_ - 1)) * C_ + c) * S2_;

    const float4 v = *(const float4*)(d + dbase + s);
    const int4  f  = *(const int4*)(flags + s);
    const int4  p  = *(const int4*)(poi + s);

    float4 o = v;
    if (f.x == 0) o.x += d[dbase + p.x];
    if (f.y == 0) o.y += d[dbase + p.y];
    if (f.z == 0) o.z += d[dbase + p.z];
    if (f.w == 0) o.w += d[dbase + p.w];

    *(float4*)(out + i) = o;
}

extern "C" void kernel_launch(void* const* d_in, const int* in_sizes, int n_in,
                              void* d_out, int out_size, void* d_ws, size_t ws_size,
                              hipStream_t stream) {
    const float* d   = (const float*)d_in[0];
    const int*   m   = (const int*)d_in[1];
    const int*   poi = (const int*)d_in[2];
    float*       out = (float*)d_out;
    int*         flags = (int*)d_ws;   // 1024 ints = 4 KB of workspace

    // d_ws is re-poisoned to 0xAA before every timed call -> must zero-init.
    hipMemsetAsync(flags, 0, S2_ * sizeof(int), stream);

    mask_reduce<<<dim3(256), dim3(256), 0, stream>>>(m, flags);

    // B*C*S2 / (256 threads * 4 elems) = 4096 blocks
    auxcmp_main<<<dim3((B_ * C_ * S2_) / (256 * 4)), dim3(256), 0, stream>>>(
        d, flags, poi, out);
}